// Round 7
// baseline (619.812 us; speedup 1.0000x reference)
//
#include <hip/hip_runtime.h>
#include <hip/hip_bf16.h>
#include <stdint.h>

typedef unsigned short ushortT;
typedef __bf16 bf16x8 __attribute__((ext_vector_type(8)));
typedef float f32x4 __attribute__((ext_vector_type(4)));
typedef unsigned short u16x8 __attribute__((ext_vector_type(8)));

#define N_TOK 131072
#define NSEG  256

__device__ __forceinline__ uint32_t f2bf(float f) {
  union { float f; uint32_t u; } c; c.f = f;
  uint32_t u = c.u;
  u += 0x7fffu + ((u >> 16) & 1u);   // RNE
  return u >> 16;
}
__device__ __forceinline__ float bf2f(uint32_t b) {
  union { uint32_t u; float f; } c; c.u = b << 16;
  return c.f;
}

__device__ __forceinline__ void gload_lds16(const void* g, void* l) {
  __builtin_amdgcn_global_load_lds(
      (const __attribute__((address_space(1))) void*)g,
      (__attribute__((address_space(3))) void*)l, 16, 0, 0);
}

// ---------------- prep kernels ----------------

__global__ void convert_bf16_kernel(const float* __restrict__ X, ushortT* __restrict__ Xb, int n4) {
  int i = blockIdx.x * 256 + threadIdx.x;
  const int stride = gridDim.x * 256;
  for (int idx = i; idx < n4; idx += stride) {
    const float4 v = ((const float4*)X)[idx];
    uint2 pk;
    pk.x = f2bf(v.x) | (f2bf(v.y) << 16);
    pk.y = f2bf(v.z) | (f2bf(v.w) << 16);
    ((uint2*)Xb)[idx] = pk;
  }
}

// WT[n*Kd + k] = bf16(W[k*Nd + n]);  W is [Kd][Nd] row-major
__global__ void transpose_bf16_kernel(const float* __restrict__ W, ushortT* __restrict__ WT,
                                      int Kd, int Nd) {
  int i = blockIdx.x * 256 + threadIdx.x;
  if (i < Kd * Nd) {
    int n = i / Kd, k = i % Kd;
    WT[i] = (ushortT)f2bf(W[(size_t)k * Nd + n]);
  }
}

// weff[c*8+h] = sum_d Wk[c,h*128+d]*Wq[h,d] / sqrt(128),  c in [0,640)
__global__ void weff_kernel(const float* __restrict__ Wk, const float* __restrict__ Wq,
                            float* __restrict__ weff) {
  const int c = blockIdx.x;       // 640
  const int lane = threadIdx.x;   // 64
  const float rs = 0.08838834764831845f;
#pragma unroll
  for (int h = 0; h < 8; ++h) {
    float acc = Wk[(size_t)c * 1024 + h * 128 + lane] * Wq[h * 128 + lane]
              + Wk[(size_t)c * 1024 + h * 128 + 64 + lane] * Wq[h * 128 + 64 + lane];
#pragma unroll
    for (int off = 32; off >= 1; off >>= 1) acc += __shfl_xor(acc, off, 64);
    if (lane == 0) weff[c * 8 + h] = acc * rs;
  }
}

// gbnd[s] = first index with seg[i] >= s, s in [0, 256]; gbnd[256] = N_TOK
__global__ void seg_bounds_kernel(const int* __restrict__ seg, int* __restrict__ gbnd) {
  const int s = (int)threadIdx.x + (int)blockIdx.x * 512;
  if (s > NSEG) return;
  int lo = 0, hi = N_TOK;
  while (lo < hi) { int m = (lo + hi) >> 1; if (seg[m] < s) lo = m + 1; else hi = m; }
  gbnd[s] = lo;
}

// ---------------- 2-phase GEMM: C[M,512] = relu?(A[M,K] @ W + bias) ----------------
// m201 geometry: tile 256x256, BK=64, 8 waves (2M x 4N), wave tile 128x64
// (acc[8][4]). LDS: double buffer x (A[256][64] + B[256][64]) = 128 KB.
// T3-minimum schedule: STAGE(j+1) -> ds_read+MFMA(j) -> lgkmcnt(0)+vmcnt(0)
// -> s_barrier. XOR swizzle: chunk c of row r stored at c^(r&7) (pre-swizzled
// global source, swizzled ds_read).

template <int K, bool RELU, bool BIAS>
__global__ __launch_bounds__(512, 2)
void gemm_2ph_kernel(const ushortT* __restrict__ A, const ushortT* __restrict__ BT,
                     const float* __restrict__ bias, ushortT* __restrict__ C) {
  __shared__ char lds[2 * 65536];
  constexpr int NT = K / 64;

  // XCD-aware swizzle (nwg multiple of 8)
  const int nwg  = (int)gridDim.x;
  const int cpx  = nwg >> 3;
  const int flat = (int)blockIdx.x;
  const int swz  = (flat & 7) * cpx + (flat >> 3);
  const int bm   = swz >> 1;   // 256-row blocks
  const int bn   = swz & 1;    // 2 col blocks of 256

  const int t = (int)threadIdx.x;
  const int w = t >> 6, lane = t & 63;
  const int wm = w >> 2, wn = w & 3;
  const int q = lane >> 4, lr = lane & 15;

  // staging: pass p covers tile-rows [p*64, p*64+64); thread t -> row p*64+(t>>3),
  // LDS chunk (t&7); global source chunk = (t&7) ^ (row&7)
  const int srow   = t >> 3;
  const int schunk = (t & 7) ^ (srow & 7);
  const ushortT* Ag = A  + (size_t)(bm * 256 + srow) * K + schunk * 8;
  const ushortT* Bg = BT + (size_t)(bn * 256 + srow) * K + schunk * 8;

  f32x4 acc[8][4];
#pragma unroll
  for (int i = 0; i < 8; ++i)
#pragma unroll
    for (int j = 0; j < 4; ++j) acc[i][j] = 0.f;

#define STAGE_TILE(buf, tile)                                                   \
  {                                                                             \
    char* _la = lds + (buf) * 65536 + t * 16;                                   \
    const ushortT* _ga = Ag + (tile) * 64;                                      \
    _Pragma("unroll")                                                           \
    for (int _p = 0; _p < 4; ++_p)                                              \
      gload_lds16(_ga + (size_t)_p * 64 * K, _la + _p * 8192);                  \
    char* _lb = _la + 32768;                                                    \
    const ushortT* _gb = Bg + (tile) * 64;                                      \
    _Pragma("unroll")                                                           \
    for (int _p = 0; _p < 4; ++_p)                                              \
      gload_lds16(_gb + (size_t)_p * 64 * K, _lb + _p * 8192);                  \
  }

  STAGE_TILE(0, 0);
  asm volatile("s_waitcnt vmcnt(0)" ::: "memory");
  __builtin_amdgcn_s_barrier();
  asm volatile("" ::: "memory");

  int cur = 0;
#pragma unroll 1
  for (int j = 0; j < NT; ++j) {
    if (j + 1 < NT) STAGE_TILE(1 - cur, j + 1);

    const char* sa = lds + cur * 65536;
    const char* sb = sa + 32768;
#pragma unroll
    for (int kk = 0; kk < 2; ++kk) {
      const int cc = ((kk * 4 + q) ^ (lr & 7)) << 4;
      bf16x8 a[8], b[4];
#pragma unroll
      for (int m = 0; m < 8; ++m)
        a[m] = *(const bf16x8*)(sa + (wm * 128 + m * 16 + lr) * 128 + cc);
#pragma unroll
      for (int n = 0; n < 4; ++n)
        b[n] = *(const bf16x8*)(sb + (wn * 64 + n * 16 + lr) * 128 + cc);

      __builtin_amdgcn_s_setprio(1);
#pragma unroll
      for (int n = 0; n < 4; ++n)
#pragma unroll
        for (int m = 0; m < 8; ++m)
          acc[m][n] = __builtin_amdgcn_mfma_f32_16x16x32_bf16(a[m], b[n], acc[m][n], 0, 0, 0);
      __builtin_amdgcn_s_setprio(0);
    }

    if (j + 1 < NT) {
      asm volatile("s_waitcnt lgkmcnt(0)" ::: "memory");
      asm volatile("s_waitcnt vmcnt(0)" ::: "memory");
      __builtin_amdgcn_s_barrier();
      asm volatile("" ::: "memory");
      cur ^= 1;
    }
  }
#undef STAGE_TILE

  // C/D layout (validated R3/R6): col = base + (lane&15), row = base + q*4 + r
  const int row0 = bm * 256 + wm * 128 + q * 4;
  const int col0 = bn * 256 + wn * 64 + lr;
#pragma unroll
  for (int n = 0; n < 4; ++n) {
    const int col = col0 + n * 16;
    const float bvv = BIAS ? bias[col] : 0.f;
#pragma unroll
    for (int m = 0; m < 8; ++m) {
#pragma unroll
      for (int r = 0; r < 4; ++r) {
        float v = acc[m][n][r] + bvv;
        if (RELU) v = fmaxf(v, 0.f);
        C[(size_t)(row0 + m * 16 + r) * 512 + col] = (ushortT)f2bf(v);
      }
    }
  }
}

// ---------------- segment prefix-mean scan, carry derived from global bounds ----
// grid = NSEG*2 blocks of 128 threads; block (s, colgrp) owns words
// [colgrp*128, colgrp*128+128) of segment s. No carry_cnt (derived from gbnd).

__global__ __launch_bounds__(128)
void scan_kernel(const ushortT* __restrict__ z, ushortT* __restrict__ gout,
                 const int* __restrict__ gbnd, const float* __restrict__ br,
                 float* __restrict__ carry_sum, int c0, int rows) {
  const int s  = (int)blockIdx.x >> 1;
  const int cg = (int)blockIdx.x & 1;
  const int t  = (int)threadIdx.x + cg * 128;   // word (2 cols) owner

  const int gb0 = gbnd[s], gb1 = gbnd[s + 1];
  int beg = gb0 > c0 ? gb0 : c0;
  int end = gb1 < c0 + rows ? gb1 : c0 + rows;
  if (end <= beg) return;
  // rows of this segment strictly before c0:
  int cb = c0 - gb0; if (cb < 0) cb = 0;
  const int seglen = gb1 - gb0; if (cb > seglen) cb = seglen;
  const int cntBase = cb;

  const float b0 = br[2 * t], b1v = br[2 * t + 1];
  float a0 = carry_sum[s * 512 + 2 * t];
  float a1 = carry_sum[s * 512 + 2 * t + 1];
  const uint32_t* __restrict__ zp = (const uint32_t*)z;
  uint32_t* __restrict__ gp = (uint32_t*)gout;

  constexpr int P = 32;   // prefetch depth (static-indexed ring)
  uint32_t buf[P];
#pragma unroll
  for (int p = 0; p < P; ++p)
    buf[p] = (beg + p < end) ? zp[(size_t)(beg + p - c0) * 256 + t] : 0u;

  int base = beg;
  for (; base + 2 * P <= end; base += P) {
#pragma unroll
    for (int p = 0; p < P; ++p) {
      const int r = base + p;
      const uint32_t v = buf[p];
      buf[p] = zp[(size_t)(r + P - c0) * 256 + t];
      a0 += bf2f(v & 0xffffu);
      a1 += bf2f(v >> 16);
      const float inv = 1.0f / (float)(cntBase + r - beg + 1);
      const float g0 = fmaxf(fmaf(a0, inv, b0), 0.f);
      const float g1 = fmaxf(fmaf(a1, inv, b1v), 0.f);
      gp[(size_t)(r - c0) * 256 + t] = f2bf(g0) | (f2bf(g1) << 16);
    }
  }
  for (; base < end; base += P) {
#pragma unroll
    for (int p = 0; p < P; ++p) {
      const int r = base + p;
      if (r < end) {
        const uint32_t v = buf[p];
        buf[p] = (r + P < end) ? zp[(size_t)(r + P - c0) * 256 + t] : 0u;
        a0 += bf2f(v & 0xffffu);
        a1 += bf2f(v >> 16);
        const float inv = 1.0f / (float)(cntBase + r - beg + 1);
        const float g0 = fmaxf(fmaf(a0, inv, b0), 0.f);
        const float g1 = fmaxf(fmaf(a1, inv, b1v), 0.f);
        gp[(size_t)(r - c0) * 256 + t] = f2bf(g0) | (f2bf(g1) << 16);
      }
    }
  }

  carry_sum[s * 512 + 2 * t]     = a0;
  carry_sum[s * 512 + 2 * t + 1] = a1;
}

// ---------------- final: out[n,h] = X[n,:]@weff[0:128,h] + g[n,:]@weff[128:640,h] ----------------

__global__ __launch_bounds__(256)
void final_kernel(const float* __restrict__ X, const ushortT* __restrict__ g,
                  const float* __restrict__ weff, float* __restrict__ out, int rows) {
  const int t = (int)threadIdx.x;
  const int wv = t >> 6, lane = t & 63;

  float wx0[8], wx1[8], wg[8][8];
#pragma unroll
  for (int h = 0; h < 8; ++h) {
    wx0[h] = weff[(2 * lane) * 8 + h];
    wx1[h] = weff[(2 * lane + 1) * 8 + h];
  }
#pragma unroll
  for (int j = 0; j < 8; ++j)
#pragma unroll
    for (int h = 0; h < 8; ++h)
      wg[j][h] = weff[(128 + 8 * lane + j) * 8 + h];

  for (int row = (int)blockIdx.x * 4 + wv; row < rows; row += (int)gridDim.x * 4) {
    const float2 xv = *(const float2*)&X[(size_t)row * 128 + 2 * lane];
    const u16x8 gv = *(const u16x8*)&g[(size_t)row * 512 + 8 * lane];
    float pp[8];
#pragma unroll
    for (int h = 0; h < 8; ++h) pp[h] = xv.x * wx0[h] + xv.y * wx1[h];
#pragma unroll
    for (int j = 0; j < 8; ++j) {
      const float f = bf2f((uint32_t)gv[j]);
#pragma unroll
      for (int h = 0; h < 8; ++h) pp[h] = fmaf(f, wg[j][h], pp[h]);
    }
#pragma unroll
    for (int off = 32; off >= 1; off >>= 1) {
#pragma unroll
      for (int h = 0; h < 8; ++h) pp[h] += __shfl_xor(pp[h], off, 64);
    }
    if (lane == 0) {
#pragma unroll
      for (int h = 0; h < 8; ++h) out[(size_t)row * 8 + h] = pp[h];
    }
  }
}

// ---------------- launch ----------------

extern "C" void kernel_launch(void* const* d_in, const int* in_sizes, int n_in,
                              void* d_out, int out_size, void* d_ws, size_t ws_size,
                              hipStream_t stream) {
  const float* X  = (const float*)d_in[0];
  const int*   sg = (const int*)d_in[1];
  const float* W1 = (const float*)d_in[2];
  const float* b1 = (const float*)d_in[3];
  const float* W2 = (const float*)d_in[4];
  const float* b2 = (const float*)d_in[5];
  const float* W3 = (const float*)d_in[6];
  const float* b3 = (const float*)d_in[7];
  const float* Wr = (const float*)d_in[8];
  const float* br = (const float*)d_in[9];
  const float* Wk = (const float*)d_in[10];
  const float* Wq = (const float*)d_in[11];
  float* out = (float*)d_out;

  const size_t szW1T  = 512 * 128 * 2;
  const size_t szWT   = 512 * 512 * 2;
  const size_t szWeff = 640 * 8 * 4;
  const size_t szCSum = NSEG * 512 * 4;
  const size_t szBnd  = (NSEG + 1) * 4;
  const size_t fixed  = szW1T + 3 * szWT + szWeff + szCSum + szBnd + 256;

  int CH = 0;
  const int cands[6] = {131072, 65536, 32768, 16384, 8192, 4096};
  for (int i = 0; i < 6; ++i) {
    const size_t need = fixed + (size_t)cands[i] * 128 * 2     // Xb chunk
                      + 2 * (size_t)cands[i] * 512 * 2;        // ping-pong
    if (need <= ws_size) { CH = cands[i]; break; }
  }
  if (CH == 0) CH = 4096;

  char* p = (char*)d_ws;
  ushortT* W1T  = (ushortT*)p; p += szW1T;
  ushortT* W2T  = (ushortT*)p; p += szWT;
  ushortT* W3T  = (ushortT*)p; p += szWT;
  ushortT* WrT  = (ushortT*)p; p += szWT;
  float*   weff = (float*)p;   p += szWeff;
  float*   cSum = (float*)p;   p += szCSum;
  int*     gbnd = (int*)p;     p += (szBnd + 255) & ~255ull;
  ushortT* Xb   = (ushortT*)p; p += (size_t)CH * 128 * 2;
  ushortT* p1   = (ushortT*)p; p += (size_t)CH * 512 * 2;
  ushortT* p2   = (ushortT*)p;

  transpose_bf16_kernel<<<(512 * 128 + 255) / 256, 256, 0, stream>>>(W1, W1T, 128, 512);
  transpose_bf16_kernel<<<(512 * 512 + 255) / 256, 256, 0, stream>>>(W2, W2T, 512, 512);
  transpose_bf16_kernel<<<(512 * 512 + 255) / 256, 256, 0, stream>>>(W3, W3T, 512, 512);
  transpose_bf16_kernel<<<(512 * 512 + 255) / 256, 256, 0, stream>>>(Wr, WrT, 512, 512);
  weff_kernel<<<640, 64, 0, stream>>>(Wk, Wq, weff);
  seg_bounds_kernel<<<1, 512, 0, stream>>>(sg, gbnd);
  hipMemsetAsync(cSum, 0, szCSum, stream);

  for (int c0 = 0; c0 < N_TOK; c0 += CH) {
    const int gG = (CH / 256) * 2;
    const int gF = (CH / 4 < 4096) ? CH / 4 : 4096;
    convert_bf16_kernel<<<2048, 256, 0, stream>>>(X + (size_t)c0 * 128, Xb, CH * 128 / 4);
    gemm_2ph_kernel<128, true,  true ><<<gG, 512, 0, stream>>>(Xb, W1T, b1, p1);
    gemm_2ph_kernel<512, true,  true ><<<gG, 512, 0, stream>>>(p1, W2T, b2, p2);
    gemm_2ph_kernel<512, true,  true ><<<gG, 512, 0, stream>>>(p2, W3T, b3, p1);
    gemm_2ph_kernel<512, false, false><<<gG, 512, 0, stream>>>(p1, WrT, nullptr, p2);
    scan_kernel<<<NSEG * 2, 128, 0, stream>>>(p2, p1, gbnd, br, cSum, c0, CH);
    final_kernel<<<gF, 256, 0, stream>>>(X + (size_t)c0 * 128, p1, weff,
                                         out + (size_t)c0 * 8, CH);
  }
}

// Round 8
// 618.590 us; speedup vs baseline: 1.0020x; 1.0020x over previous
//
#include <hip/hip_runtime.h>
#include <hip/hip_bf16.h>
#include <stdint.h>

typedef unsigned short ushortT;
typedef __bf16 bf16x8 __attribute__((ext_vector_type(8)));
typedef float f32x4 __attribute__((ext_vector_type(4)));
typedef unsigned short u16x8 __attribute__((ext_vector_type(8)));

#define N_TOK 131072
#define NSEG  256
#define RSPL  8

__device__ __forceinline__ uint32_t f2bf(float f) {
  union { float f; uint32_t u; } c; c.f = f;
  uint32_t u = c.u;
  u += 0x7fffu + ((u >> 16) & 1u);   // RNE
  return u >> 16;
}
__device__ __forceinline__ float bf2f(uint32_t b) {
  union { uint32_t u; float f; } c; c.u = b << 16;
  return c.f;
}

__device__ __forceinline__ void gload_lds16(const void* g, void* l) {
  __builtin_amdgcn_global_load_lds(
      (const __attribute__((address_space(1))) void*)g,
      (__attribute__((address_space(3))) void*)l, 16, 0, 0);
}

// ---------------- prep kernels ----------------

__global__ void convert_bf16_kernel(const float* __restrict__ X, ushortT* __restrict__ Xb, int n4) {
  int i = blockIdx.x * 256 + threadIdx.x;
  const int stride = gridDim.x * 256;
  for (int idx = i; idx < n4; idx += stride) {
    const float4 v = ((const float4*)X)[idx];
    uint2 pk;
    pk.x = f2bf(v.x) | (f2bf(v.y) << 16);
    pk.y = f2bf(v.z) | (f2bf(v.w) << 16);
    ((uint2*)Xb)[idx] = pk;
  }
}

// WT[n*Kd + k] = bf16(W[k*Nd + n]);  W is [Kd][Nd] row-major
__global__ void transpose_bf16_kernel(const float* __restrict__ W, ushortT* __restrict__ WT,
                                      int Kd, int Nd) {
  int i = blockIdx.x * 256 + threadIdx.x;
  if (i < Kd * Nd) {
    int n = i / Kd, k = i % Kd;
    WT[i] = (ushortT)f2bf(W[(size_t)k * Nd + n]);
  }
}

// weff[c*8+h] = sum_d Wk[c,h*128+d]*Wq[h,d] / sqrt(128),  c in [0,640)
__global__ void weff_kernel(const float* __restrict__ Wk, const float* __restrict__ Wq,
                            float* __restrict__ weff) {
  const int c = blockIdx.x;       // 640
  const int lane = threadIdx.x;   // 64
  const float rs = 0.08838834764831845f;
#pragma unroll
  for (int h = 0; h < 8; ++h) {
    float acc = Wk[(size_t)c * 1024 + h * 128 + lane] * Wq[h * 128 + lane]
              + Wk[(size_t)c * 1024 + h * 128 + 64 + lane] * Wq[h * 128 + 64 + lane];
#pragma unroll
    for (int off = 32; off >= 1; off >>= 1) acc += __shfl_xor(acc, off, 64);
    if (lane == 0) weff[c * 8 + h] = acc * rs;
  }
}

// gbnd[s] = first index with seg[i] >= s, s in [0, 256]
__global__ void seg_bounds_kernel(const int* __restrict__ seg, int* __restrict__ gbnd) {
  const int s = (int)threadIdx.x + (int)blockIdx.x * 512;
  if (s > NSEG) return;
  int lo = 0, hi = N_TOK;
  while (lo < hi) { int m = (lo + hi) >> 1; if (seg[m] < s) lo = m + 1; else hi = m; }
  gbnd[s] = lo;
}

// ---------------- ring-4 GEMM: C[M,512] = relu?(A[M,K] @ W + bias) ----------------
// Tile 256x256, BK=32, 8 waves (2M x 4N), wave tile 128x64 (acc[8][4]).
// LDS: 4-slot ring, slot = A[256][32] (16KB) + B[256][32] (16KB) = 32KB.
// Counted-vmcnt schedule (T3/T4): stage-ahead 3 slots; per step: vmcnt(8) ->
// barrier -> stage(j+3) -> ds_read(slot j) -> setprio+32 MFMA. Never drains
// vmcnt in steady state; one barrier per K-step.
// Ledger: stage(j+3) overwrites slot (j-1)%4 whose readers (iter j-1 ds_reads)
// drained via compiler lgkmcnt before iter j-1's MFMAs, all before this barrier.
// Slot-j reads valid: each wave's own slot-j loads forced landed by vmcnt(8)
// (oldest-first), then barrier publishes all waves' loads.
// Swizzle: 16B chunk c of row r stored at c^(r&3); pre-swizzled global source,
// swizzled ds_read (same involution). 2-way bank aliasing = free (m136).

template <int K, bool RELU, bool BIAS>
__global__ __launch_bounds__(512, 2)
void gemm_ring4_kernel(const ushortT* __restrict__ A, const ushortT* __restrict__ BT,
                       const float* __restrict__ bias, ushortT* __restrict__ C) {
  __shared__ char lds[4 * 32768];
  constexpr int NT = K / 32;

  // XCD-aware swizzle (nwg multiple of 8)
  const int nwg  = (int)gridDim.x;
  const int cpx  = nwg >> 3;
  const int flat = (int)blockIdx.x;
  const int swz  = (flat & 7) * cpx + (flat >> 3);
  const int bm   = swz >> 1;   // 256-row blocks
  const int bn   = swz & 1;    // 2 col blocks of 256

  const int t = (int)threadIdx.x;
  const int w = t >> 6, lane = t & 63;
  const int wm = w >> 2, wn = w & 3;
  const int q = lane >> 4, lr = lane & 15;

  // staging: thread t -> LDS row t>>2 (+128 on pass 1), stored chunk t&3;
  // global source chunk = (t&3) ^ (row&3)
  const int srow   = t >> 2;
  const int schunk = (t & 3) ^ (srow & 3);
  const ushortT* Ag = A  + (size_t)(bm * 256 + srow) * K + schunk * 8;
  const ushortT* Bg = BT + (size_t)(bn * 256 + srow) * K + schunk * 8;

  f32x4 acc[8][4];
#pragma unroll
  for (int i = 0; i < 8; ++i)
#pragma unroll
    for (int j = 0; j < 4; ++j) acc[i][j] = 0.f;

#define STAGE(tile)                                                             \
  {                                                                             \
    char* _d = lds + ((tile) & 3) * 32768 + t * 16;                             \
    const ushortT* _ga = Ag + (tile) * 32;                                      \
    gload_lds16(_ga, _d);                                                       \
    gload_lds16(_ga + (size_t)128 * K, _d + 8192);                              \
    const ushortT* _gb = Bg + (tile) * 32;                                      \
    gload_lds16(_gb, _d + 16384);                                               \
    gload_lds16(_gb + (size_t)128 * K, _d + 24576);                             \
  }

  // prologue: 3 slots in flight (12 loads)
  STAGE(0);
  STAGE(1);
  STAGE(2);

  const int cc = (q ^ (lr & 3)) << 4;   // swizzled chunk byte offset
  const int aro = (wm * 128 + lr) * 64; // + m*1024
  const int bro = 16384 + (wn * 64 + lr) * 64;  // + n*1024

#pragma unroll 1
  for (int j = 0; j < NT; ++j) {
    if (j + 2 < NT)      asm volatile("s_waitcnt vmcnt(8)" ::: "memory");
    else if (j + 1 < NT) asm volatile("s_waitcnt vmcnt(4)" ::: "memory");
    else                 asm volatile("s_waitcnt vmcnt(0)" ::: "memory");
    __builtin_amdgcn_s_barrier();
    asm volatile("" ::: "memory");

    if (j + 3 < NT) STAGE(j + 3);

    const char* sl = lds + (j & 3) * 32768;
    bf16x8 a[8], b[4];
#pragma unroll
    for (int m = 0; m < 8; ++m)
      a[m] = *(const bf16x8*)(sl + aro + m * 1024 + cc);
#pragma unroll
    for (int n = 0; n < 4; ++n)
      b[n] = *(const bf16x8*)(sl + bro + n * 1024 + cc);

    __builtin_amdgcn_s_setprio(1);
#pragma unroll
    for (int n = 0; n < 4; ++n)
#pragma unroll
      for (int m = 0; m < 8; ++m)
        acc[m][n] = __builtin_amdgcn_mfma_f32_16x16x32_bf16(a[m], b[n], acc[m][n], 0, 0, 0);
    __builtin_amdgcn_s_setprio(0);
  }
#undef STAGE

  // C/D layout (validated R3-R7): col = base + (lane&15), row = base + q*4 + r
  const int row0 = bm * 256 + wm * 128 + q * 4;
  const int col0 = bn * 256 + wn * 64 + lr;
#pragma unroll
  for (int n = 0; n < 4; ++n) {
    const int col = col0 + n * 16;
    const float bvv = BIAS ? bias[col] : 0.f;
#pragma unroll
    for (int m = 0; m < 8; ++m) {
#pragma unroll
      for (int r = 0; r < 4; ++r) {
        float v = acc[m][n][r] + bvv;
        if (RELU) v = fmaxf(v, 0.f);
        C[(size_t)(row0 + m * 16 + r) * 512 + col] = (ushortT)f2bf(v);
      }
    }
  }
}

// ---------------- two-pass segment prefix-mean ----------------
// Pass 1: block (s, rge) sums z over its row-range -> part[s][rge][word][2]
// Pass 2: block (s, rge) start = carry_in + sum(part[s][<rge]); walks its rows.
// Carry ping-pongs between two buffers across chunks (no RMW race).

__global__ __launch_bounds__(256)
void seg_sum_kernel(const ushortT* __restrict__ z, const int* __restrict__ gbnd,
                    float* __restrict__ part, int c0, int rows) {
  const int s  = (int)blockIdx.x >> 3;
  const int rg = (int)blockIdx.x & 7;
  const int t  = (int)threadIdx.x;

  const int gb0 = gbnd[s], gb1 = gbnd[s + 1];
  int beg = gb0 > c0 ? gb0 : c0;
  int end = gb1 < c0 + rows ? gb1 : c0 + rows;
  int len = end - beg; if (len < 0) len = 0;
  const int r0 = beg + ((len * rg) >> 3);
  const int r1 = beg + ((len * (rg + 1)) >> 3);

  float a0 = 0.f, a1 = 0.f;
  const uint32_t* __restrict__ zp = (const uint32_t*)z;
  int r = r0;
  for (; r + 8 <= r1; r += 8) {
    uint32_t v[8];
#pragma unroll
    for (int i = 0; i < 8; ++i) v[i] = zp[(size_t)(r + i - c0) * 256 + t];
#pragma unroll
    for (int i = 0; i < 8; ++i) { a0 += bf2f(v[i] & 0xffffu); a1 += bf2f(v[i] >> 16); }
  }
  for (; r < r1; ++r) {
    const uint32_t v = zp[(size_t)(r - c0) * 256 + t];
    a0 += bf2f(v & 0xffffu); a1 += bf2f(v >> 16);
  }
  float2 pv; pv.x = a0; pv.y = a1;
  ((float2*)part)[(s * 8 + rg) * 256 + t] = pv;
}

__global__ __launch_bounds__(256)
void seg_scan2_kernel(const ushortT* __restrict__ z, ushortT* __restrict__ gout,
                      const int* __restrict__ gbnd, const float* __restrict__ br,
                      const float* __restrict__ part,
                      const float* __restrict__ cin, float* __restrict__ cout,
                      int c0, int rows) {
  const int s  = (int)blockIdx.x >> 3;
  const int rg = (int)blockIdx.x & 7;
  const int t  = (int)threadIdx.x;

  const int gb0 = gbnd[s], gb1 = gbnd[s + 1];
  int beg = gb0 > c0 ? gb0 : c0;
  int end = gb1 < c0 + rows ? gb1 : c0 + rows;
  int len = end - beg; if (len < 0) len = 0;
  const int r0 = beg + ((len * rg) >> 3);
  const int r1 = beg + ((len * (rg + 1)) >> 3);

  const float2 cv = ((const float2*)cin)[s * 256 + t];
  float a0 = cv.x, a1 = cv.y;
  for (int q2 = 0; q2 < rg; ++q2) {
    const float2 pv = ((const float2*)part)[(s * 8 + q2) * 256 + t];
    a0 += pv.x; a1 += pv.y;
  }
  int cb = c0 - gb0; if (cb < 0) cb = 0;
  const int seglen = gb1 - gb0; if (cb > seglen) cb = seglen;
  const int cnt0 = cb + (r0 - beg);   // count before row r0

  const float b0 = br[2 * t], b1v = br[2 * t + 1];
  const uint32_t* __restrict__ zp = (const uint32_t*)z;
  uint32_t* __restrict__ gp = (uint32_t*)gout;

  int r = r0;
  for (; r + 8 <= r1; r += 8) {
    uint32_t v[8];
#pragma unroll
    for (int i = 0; i < 8; ++i) v[i] = zp[(size_t)(r + i - c0) * 256 + t];
#pragma unroll
    for (int i = 0; i < 8; ++i) {
      a0 += bf2f(v[i] & 0xffffu);
      a1 += bf2f(v[i] >> 16);
      const float inv = 1.0f / (float)(cnt0 + (r + i) - r0 + 1);
      const float g0 = fmaxf(fmaf(a0, inv, b0), 0.f);
      const float g1 = fmaxf(fmaf(a1, inv, b1v), 0.f);
      gp[(size_t)(r + i - c0) * 256 + t] = f2bf(g0) | (f2bf(g1) << 16);
    }
  }
  for (; r < r1; ++r) {
    const uint32_t v = zp[(size_t)(r - c0) * 256 + t];
    a0 += bf2f(v & 0xffffu);
    a1 += bf2f(v >> 16);
    const float inv = 1.0f / (float)(cnt0 + r - r0 + 1);
    const float g0 = fmaxf(fmaf(a0, inv, b0), 0.f);
    const float g1 = fmaxf(fmaf(a1, inv, b1v), 0.f);
    gp[(size_t)(r - c0) * 256 + t] = f2bf(g0) | (f2bf(g1) << 16);
  }

  if (rg == 7) {   // final range: a = carry_in + full chunk sum
    float2 co; co.x = a0; co.y = a1;
    ((float2*)cout)[s * 256 + t] = co;
  }
}

// ---------------- final: out[n,h] = X[n,:]@weff[0:128,h] + g[n,:]@weff[128:640,h] ----------------

__global__ __launch_bounds__(256)
void final_kernel(const float* __restrict__ X, const ushortT* __restrict__ g,
                  const float* __restrict__ weff, float* __restrict__ out, int rows) {
  const int t = (int)threadIdx.x;
  const int wv = t >> 6, lane = t & 63;

  float wx0[8], wx1[8], wg[8][8];
#pragma unroll
  for (int h = 0; h < 8; ++h) {
    wx0[h] = weff[(2 * lane) * 8 + h];
    wx1[h] = weff[(2 * lane + 1) * 8 + h];
  }
#pragma unroll
  for (int j = 0; j < 8; ++j)
#pragma unroll
    for (int h = 0; h < 8; ++h)
      wg[j][h] = weff[(128 + 8 * lane + j) * 8 + h];

  for (int row = (int)blockIdx.x * 4 + wv; row < rows; row += (int)gridDim.x * 4) {
    const float2 xv = *(const float2*)&X[(size_t)row * 128 + 2 * lane];
    const u16x8 gv = *(const u16x8*)&g[(size_t)row * 512 + 8 * lane];
    float pp[8];
#pragma unroll
    for (int h = 0; h < 8; ++h) pp[h] = xv.x * wx0[h] + xv.y * wx1[h];
#pragma unroll
    for (int j = 0; j < 8; ++j) {
      const float f = bf2f((uint32_t)gv[j]);
#pragma unroll
      for (int h = 0; h < 8; ++h) pp[h] = fmaf(f, wg[j][h], pp[h]);
    }
#pragma unroll
    for (int off = 32; off >= 1; off >>= 1) {
#pragma unroll
      for (int h = 0; h < 8; ++h) pp[h] += __shfl_xor(pp[h], off, 64);
    }
    if (lane == 0) {
#pragma unroll
      for (int h = 0; h < 8; ++h) out[(size_t)row * 8 + h] = pp[h];
    }
  }
}

// ---------------- launch ----------------

extern "C" void kernel_launch(void* const* d_in, const int* in_sizes, int n_in,
                              void* d_out, int out_size, void* d_ws, size_t ws_size,
                              hipStream_t stream) {
  const float* X  = (const float*)d_in[0];
  const int*   sg = (const int*)d_in[1];
  const float* W1 = (const float*)d_in[2];
  const float* b1 = (const float*)d_in[3];
  const float* W2 = (const float*)d_in[4];
  const float* b2 = (const float*)d_in[5];
  const float* W3 = (const float*)d_in[6];
  const float* b3 = (const float*)d_in[7];
  const float* Wr = (const float*)d_in[8];
  const float* br = (const float*)d_in[9];
  const float* Wk = (const float*)d_in[10];
  const float* Wq = (const float*)d_in[11];
  float* out = (float*)d_out;

  const size_t szW1T  = 512 * 128 * 2;
  const size_t szWT   = 512 * 512 * 2;
  const size_t szWeff = 640 * 8 * 4;
  const size_t szPart = (size_t)NSEG * RSPL * 256 * 2 * 4;   // 4 MB
  const size_t szCar  = (size_t)NSEG * 256 * 2 * 4;          // 512 KB each
  const size_t szBnd  = (NSEG + 1) * 4;
  const size_t fixed  = szW1T + 3 * szWT + szWeff + szPart + 2 * szCar + szBnd + 256;

  int CH = 0;
  const int cands[6] = {131072, 65536, 32768, 16384, 8192, 4096};
  for (int i = 0; i < 6; ++i) {
    const size_t need = fixed + (size_t)cands[i] * 128 * 2     // Xb chunk
                      + 2 * (size_t)cands[i] * 512 * 2;        // ping-pong
    if (need <= ws_size) { CH = cands[i]; break; }
  }
  if (CH == 0) CH = 4096;

  char* p = (char*)d_ws;
  ushortT* W1T  = (ushortT*)p; p += szW1T;
  ushortT* W2T  = (ushortT*)p; p += szWT;
  ushortT* W3T  = (ushortT*)p; p += szWT;
  ushortT* WrT  = (ushortT*)p; p += szWT;
  float*   weff = (float*)p;   p += szWeff;
  float*   part = (float*)p;   p += szPart;
  float*   carA = (float*)p;   p += szCar;
  float*   carB = (float*)p;   p += szCar;
  int*     gbnd = (int*)p;     p += (szBnd + 255) & ~255ull;
  ushortT* Xb   = (ushortT*)p; p += (size_t)CH * 128 * 2;
  ushortT* p1   = (ushortT*)p; p += (size_t)CH * 512 * 2;
  ushortT* p2   = (ushortT*)p;

  transpose_bf16_kernel<<<(512 * 128 + 255) / 256, 256, 0, stream>>>(W1, W1T, 128, 512);
  transpose_bf16_kernel<<<(512 * 512 + 255) / 256, 256, 0, stream>>>(W2, W2T, 512, 512);
  transpose_bf16_kernel<<<(512 * 512 + 255) / 256, 256, 0, stream>>>(W3, W3T, 512, 512);
  transpose_bf16_kernel<<<(512 * 512 + 255) / 256, 256, 0, stream>>>(Wr, WrT, 512, 512);
  weff_kernel<<<640, 64, 0, stream>>>(Wk, Wq, weff);
  seg_bounds_kernel<<<1, 512, 0, stream>>>(sg, gbnd);
  hipMemsetAsync(carA, 0, szCar, stream);

  int par = 0;
  for (int c0 = 0; c0 < N_TOK; c0 += CH) {
    const int gG = (CH / 256) * 2;
    const int gF = (CH / 4 < 4096) ? CH / 4 : 4096;
    float* cin  = par ? carB : carA;
    float* cout = par ? carA : carB;
    convert_bf16_kernel<<<2048, 256, 0, stream>>>(X + (size_t)c0 * 128, Xb, CH * 128 / 4);
    gemm_ring4_kernel<128, true,  true ><<<gG, 512, 0, stream>>>(Xb, W1T, b1, p1);
    gemm_ring4_kernel<512, true,  true ><<<gG, 512, 0, stream>>>(p1, W2T, b2, p2);
    gemm_ring4_kernel<512, true,  true ><<<gG, 512, 0, stream>>>(p2, W3T, b3, p1);
    gemm_ring4_kernel<512, false, false><<<gG, 512, 0, stream>>>(p1, WrT, nullptr, p2);
    seg_sum_kernel <<<NSEG * RSPL, 256, 0, stream>>>(p2, gbnd, part, c0, CH);
    seg_scan2_kernel<<<NSEG * RSPL, 256, 0, stream>>>(p2, p1, gbnd, br, part,
                                                      cin, cout, c0, CH);
    final_kernel<<<gF, 256, 0, stream>>>(X + (size_t)c0 * 128, p1, weff,
                                         out + (size_t)c0 * 8, CH);
    par ^= 1;
  }
}

// Round 9
// 502.804 us; speedup vs baseline: 1.2327x; 1.2303x over previous
//
#include <hip/hip_runtime.h>
#include <hip/hip_bf16.h>
#include <stdint.h>

typedef unsigned short ushortT;
typedef __bf16 bf16x8 __attribute__((ext_vector_type(8)));
typedef float f32x4 __attribute__((ext_vector_type(4)));
typedef unsigned short u16x8 __attribute__((ext_vector_type(8)));

#define N_TOK 131072
#define NSEG  256
#define RSPL  8

__device__ __forceinline__ uint32_t f2bf(float f) {
  union { float f; uint32_t u; } c; c.f = f;
  uint32_t u = c.u;
  u += 0x7fffu + ((u >> 16) & 1u);   // RNE
  return u >> 16;
}
__device__ __forceinline__ float bf2f(uint32_t b) {
  union { uint32_t u; float f; } c; c.u = b << 16;
  return c.f;
}

__device__ __forceinline__ void gload_lds16(const void* g, void* l) {
  __builtin_amdgcn_global_load_lds(
      (const __attribute__((address_space(1))) void*)g,
      (__attribute__((address_space(3))) void*)l, 16, 0, 0);
}

// ---------------- prep kernels ----------------

// WT[n*Kd + k] = bf16(W[k*Nd + n]);  W is [Kd][Nd] row-major
__global__ void transpose_bf16_kernel(const float* __restrict__ W, ushortT* __restrict__ WT,
                                      int Kd, int Nd) {
  int i = blockIdx.x * 256 + threadIdx.x;
  if (i < Kd * Nd) {
    int n = i / Kd, k = i % Kd;
    WT[i] = (ushortT)f2bf(W[(size_t)k * Nd + n]);
  }
}

// weff[c*8+h] = sum_d Wk[c,h*128+d]*Wq[h,d] / sqrt(128),  c in [0,640)
__global__ void weff_kernel(const float* __restrict__ Wk, const float* __restrict__ Wq,
                            float* __restrict__ weff) {
  const int c = blockIdx.x;       // 640
  const int lane = threadIdx.x;   // 64
  const float rs = 0.08838834764831845f;
#pragma unroll
  for (int h = 0; h < 8; ++h) {
    float acc = Wk[(size_t)c * 1024 + h * 128 + lane] * Wq[h * 128 + lane]
              + Wk[(size_t)c * 1024 + h * 128 + 64 + lane] * Wq[h * 128 + 64 + lane];
#pragma unroll
    for (int off = 32; off >= 1; off >>= 1) acc += __shfl_xor(acc, off, 64);
    if (lane == 0) weff[c * 8 + h] = acc * rs;
  }
}

// gbnd[s] = first index with seg[i] >= s, s in [0, 256]
__global__ void seg_bounds_kernel(const int* __restrict__ seg, int* __restrict__ gbnd) {
  const int s = (int)threadIdx.x + (int)blockIdx.x * 512;
  if (s > NSEG) return;
  int lo = 0, hi = N_TOK;
  while (lo < hi) { int m = (lo + hi) >> 1; if (seg[m] < s) lo = m + 1; else hi = m; }
  gbnd[s] = lo;
}

// ---------------- m97-style GEMM: C[M,512] = relu?(A[M,K] @ W + bias) ----------------
// Tile 128x128, BK=64, 4 waves (2M x 2N), wave tile 64x64 (acc[4][4]).
// Single 64 KB... no: single-buffer LDS = A[128][64] + B[128][64] = 32 KB
// -> ~3 blocks/CU; cross-block overlap absorbs the sync drain (m97/m114).
// Swizzle: rows are 128 B = 8 chunks of 16 B; chunk c of row r stored at
// c^(r&7). Staging dest is LDS-linear (t*16); global SOURCE chunk is
// pre-swizzled; ds_read applies the same XOR -> 2-way bank aliasing (free).
// XF32: A operand is f32 (X input); reg-stage with f32->bf16 convert and
// ds_write_b128 to the same swizzled layout (fuses the old convert kernel).

template <int K, bool RELU, bool BIAS, bool XF32>
__global__ __launch_bounds__(256, 2)
void gemm_m97_kernel(const void* __restrict__ Av, const ushortT* __restrict__ BT,
                     const float* __restrict__ bias, ushortT* __restrict__ C) {
  __shared__ ushortT lA[128 * 64];
  __shared__ ushortT lB[128 * 64];
  constexpr int NT = K / 64;

  // XCD swizzle: consecutive (bm, all 4 bn) land on the same XCD -> A-panel
  // is read once into that XCD's L2 and reused by the 4 bn blocks.
  const int nwg  = (int)gridDim.x;
  const int cpx  = nwg >> 3;
  const int flat = (int)blockIdx.x;
  const int swz  = (flat & 7) * cpx + (flat >> 3);
  const int bm   = swz >> 2;
  const int bn   = swz & 3;

  const int t = (int)threadIdx.x;
  const int w = t >> 6, lane = t & 63;
  const int wm = w >> 1, wn = w & 1;
  const int q = lane >> 4, lr = lane & 15;

  // staging map: instruction j covers rows j*32..j*32+31; thread t -> row
  // j*32 + (t>>3), physical chunk t&7; source logical chunk = (t&7)^((t>>3)&7)
  const int srow = t >> 3;
  const int slc  = (t & 7) ^ (srow & 7);

  const ushortT* Ab = nullptr;
  const float*   Xf = nullptr;
  if (XF32) Xf = (const float*)Av + (size_t)(bm * 128 + srow) * 128 + slc * 8;
  else      Ab = (const ushortT*)Av + (size_t)(bm * 128 + srow) * K + slc * 8;
  const ushortT* Bg = BT + (size_t)(bn * 128 + srow) * K + slc * 8;

  f32x4 acc[4][4];
#pragma unroll
  for (int i = 0; i < 4; ++i)
#pragma unroll
    for (int j = 0; j < 4; ++j) acc[i][j] = 0.f;

  const int cc0 = (q ^ (lr & 7)) << 4;        // kk=0 swizzled chunk byte
  const int cc1 = ((4 + q) ^ (lr & 7)) << 4;  // kk=1
  const char* lAc = (const char*)lA;
  const char* lBc = (const char*)lB;

#pragma unroll 1
  for (int kt = 0; kt < NT; ++kt) {
    // ---- stage tile kt ----
    if (XF32) {
      const float* src = Xf + kt * 64;
#pragma unroll
      for (int j = 0; j < 4; ++j) {
        const float4 v0 = *(const float4*)(src + (size_t)j * 32 * 128);
        const float4 v1 = *(const float4*)(src + (size_t)j * 32 * 128 + 4);
        uint4 pk;
        pk.x = f2bf(v0.x) | (f2bf(v0.y) << 16);
        pk.y = f2bf(v0.z) | (f2bf(v0.w) << 16);
        pk.z = f2bf(v1.x) | (f2bf(v1.y) << 16);
        pk.w = f2bf(v1.z) | (f2bf(v1.w) << 16);
        *(uint4*)((char*)lA + j * 4096 + t * 16) = pk;
      }
    } else {
      const ushortT* src = Ab + kt * 64;
#pragma unroll
      for (int j = 0; j < 4; ++j)
        gload_lds16(src + (size_t)j * 32 * K, (char*)lA + j * 4096 + t * 16);
    }
    {
      const ushortT* src = Bg + kt * 64;
#pragma unroll
      for (int j = 0; j < 4; ++j)
        gload_lds16(src + (size_t)j * 32 * K, (char*)lB + j * 4096 + t * 16);
    }
    __syncthreads();   // publish tile kt (drains vmcnt/lgkm; other blocks fill)

    // ---- compute tile kt ----
    bf16x8 a0[4], a1[4], b0[4], b1[4];
#pragma unroll
    for (int m = 0; m < 4; ++m) {
      const int ro = (wm * 64 + m * 16 + lr) * 128;
      a0[m] = *(const bf16x8*)(lAc + ro + cc0);
      a1[m] = *(const bf16x8*)(lAc + ro + cc1);
    }
#pragma unroll
    for (int n = 0; n < 4; ++n) {
      const int ro = (wn * 64 + n * 16 + lr) * 128;
      b0[n] = *(const bf16x8*)(lBc + ro + cc0);
      b1[n] = *(const bf16x8*)(lBc + ro + cc1);
    }

    __builtin_amdgcn_s_setprio(1);
#pragma unroll
    for (int n = 0; n < 4; ++n)
#pragma unroll
      for (int m = 0; m < 4; ++m)
        acc[m][n] = __builtin_amdgcn_mfma_f32_16x16x32_bf16(a0[m], b0[n], acc[m][n], 0, 0, 0);
#pragma unroll
    for (int n = 0; n < 4; ++n)
#pragma unroll
      for (int m = 0; m < 4; ++m)
        acc[m][n] = __builtin_amdgcn_mfma_f32_16x16x32_bf16(a1[m], b1[n], acc[m][n], 0, 0, 0);
    __builtin_amdgcn_s_setprio(0);

    __syncthreads();   // all reads done before tile kt+1 overwrites
  }

  // C/D layout (validated R3-R8): col = base + (lane&15), row = base + q*4 + r
  const int row0 = bm * 128 + wm * 64 + q * 4;
  const int col0 = bn * 128 + wn * 64 + lr;
#pragma unroll
  for (int n = 0; n < 4; ++n) {
    const int col = col0 + n * 16;
    const float bvv = BIAS ? bias[col] : 0.f;
#pragma unroll
    for (int m = 0; m < 4; ++m) {
#pragma unroll
      for (int r = 0; r < 4; ++r) {
        float v = acc[m][n][r] + bvv;
        if (RELU) v = fmaxf(v, 0.f);
        C[(size_t)(row0 + m * 16 + r) * 512 + col] = (ushortT)f2bf(v);
      }
    }
  }
}

// ---------------- two-pass segment prefix-mean (unchanged from R8) ----------------

__global__ __launch_bounds__(256)
void seg_sum_kernel(const ushortT* __restrict__ z, const int* __restrict__ gbnd,
                    float* __restrict__ part, int c0, int rows) {
  const int s  = (int)blockIdx.x >> 3;
  const int rg = (int)blockIdx.x & 7;
  const int t  = (int)threadIdx.x;

  const int gb0 = gbnd[s], gb1 = gbnd[s + 1];
  int beg = gb0 > c0 ? gb0 : c0;
  int end = gb1 < c0 + rows ? gb1 : c0 + rows;
  int len = end - beg; if (len < 0) len = 0;
  const int r0 = beg + ((len * rg) >> 3);
  const int r1 = beg + ((len * (rg + 1)) >> 3);

  float a0 = 0.f, a1 = 0.f;
  const uint32_t* __restrict__ zp = (const uint32_t*)z;
  int r = r0;
  for (; r + 8 <= r1; r += 8) {
    uint32_t v[8];
#pragma unroll
    for (int i = 0; i < 8; ++i) v[i] = zp[(size_t)(r + i - c0) * 256 + t];
#pragma unroll
    for (int i = 0; i < 8; ++i) { a0 += bf2f(v[i] & 0xffffu); a1 += bf2f(v[i] >> 16); }
  }
  for (; r < r1; ++r) {
    const uint32_t v = zp[(size_t)(r - c0) * 256 + t];
    a0 += bf2f(v & 0xffffu); a1 += bf2f(v >> 16);
  }
  float2 pv; pv.x = a0; pv.y = a1;
  ((float2*)part)[(s * 8 + rg) * 256 + t] = pv;
}

__global__ __launch_bounds__(256)
void seg_scan2_kernel(const ushortT* __restrict__ z, ushortT* __restrict__ gout,
                      const int* __restrict__ gbnd, const float* __restrict__ br,
                      const float* __restrict__ part,
                      const float* __restrict__ cin, float* __restrict__ cout,
                      int c0, int rows) {
  const int s  = (int)blockIdx.x >> 3;
  const int rg = (int)blockIdx.x & 7;
  const int t  = (int)threadIdx.x;

  const int gb0 = gbnd[s], gb1 = gbnd[s + 1];
  int beg = gb0 > c0 ? gb0 : c0;
  int end = gb1 < c0 + rows ? gb1 : c0 + rows;
  int len = end - beg; if (len < 0) len = 0;
  const int r0 = beg + ((len * rg) >> 3);
  const int r1 = beg + ((len * (rg + 1)) >> 3);

  const float2 cv = ((const float2*)cin)[s * 256 + t];
  float a0 = cv.x, a1 = cv.y;
  for (int q2 = 0; q2 < rg; ++q2) {
    const float2 pv = ((const float2*)part)[(s * 8 + q2) * 256 + t];
    a0 += pv.x; a1 += pv.y;
  }
  int cb = c0 - gb0; if (cb < 0) cb = 0;
  const int seglen = gb1 - gb0; if (cb > seglen) cb = seglen;
  const int cnt0 = cb + (r0 - beg);

  const float b0 = br[2 * t], b1v = br[2 * t + 1];
  const uint32_t* __restrict__ zp = (const uint32_t*)z;
  uint32_t* __restrict__ gp = (uint32_t*)gout;

  int r = r0;
  for (; r + 8 <= r1; r += 8) {
    uint32_t v[8];
#pragma unroll
    for (int i = 0; i < 8; ++i) v[i] = zp[(size_t)(r + i - c0) * 256 + t];
#pragma unroll
    for (int i = 0; i < 8; ++i) {
      a0 += bf2f(v[i] & 0xffffu);
      a1 += bf2f(v[i] >> 16);
      const float inv = 1.0f / (float)(cnt0 + (r + i) - r0 + 1);
      const float g0 = fmaxf(fmaf(a0, inv, b0), 0.f);
      const float g1 = fmaxf(fmaf(a1, inv, b1v), 0.f);
      gp[(size_t)(r + i - c0) * 256 + t] = f2bf(g0) | (f2bf(g1) << 16);
    }
  }
  for (; r < r1; ++r) {
    const uint32_t v = zp[(size_t)(r - c0) * 256 + t];
    a0 += bf2f(v & 0xffffu);
    a1 += bf2f(v >> 16);
    const float inv = 1.0f / (float)(cnt0 + r - r0 + 1);
    const float g0 = fmaxf(fmaf(a0, inv, b0), 0.f);
    const float g1 = fmaxf(fmaf(a1, inv, b1v), 0.f);
    gp[(size_t)(r - c0) * 256 + t] = f2bf(g0) | (f2bf(g1) << 16);
  }

  if (rg == 7) {
    float2 co; co.x = a0; co.y = a1;
    ((float2*)cout)[s * 256 + t] = co;
  }
}

// ---------------- final: out[n,h] = X[n,:]@weff[0:128,h] + g[n,:]@weff[128:640,h] ----------------

__global__ __launch_bounds__(256)
void final_kernel(const float* __restrict__ X, const ushortT* __restrict__ g,
                  const float* __restrict__ weff, float* __restrict__ out, int rows) {
  const int t = (int)threadIdx.x;
  const int wv = t >> 6, lane = t & 63;

  float wx0[8], wx1[8], wg[8][8];
#pragma unroll
  for (int h = 0; h < 8; ++h) {
    wx0[h] = weff[(2 * lane) * 8 + h];
    wx1[h] = weff[(2 * lane + 1) * 8 + h];
  }
#pragma unroll
  for (int j = 0; j < 8; ++j)
#pragma unroll
    for (int h = 0; h < 8; ++h)
      wg[j][h] = weff[(128 + 8 * lane + j) * 8 + h];

  for (int row = (int)blockIdx.x * 4 + wv; row < rows; row += (int)gridDim.x * 4) {
    const float2 xv = *(const float2*)&X[(size_t)row * 128 + 2 * lane];
    const u16x8 gv = *(const u16x8*)&g[(size_t)row * 512 + 8 * lane];
    float pp[8];
#pragma unroll
    for (int h = 0; h < 8; ++h) pp[h] = xv.x * wx0[h] + xv.y * wx1[h];
#pragma unroll
    for (int j = 0; j < 8; ++j) {
      const float f = bf2f((uint32_t)gv[j]);
#pragma unroll
      for (int h = 0; h < 8; ++h) pp[h] = fmaf(f, wg[j][h], pp[h]);
    }
#pragma unroll
    for (int off = 32; off >= 1; off >>= 1) {
#pragma unroll
      for (int h = 0; h < 8; ++h) pp[h] += __shfl_xor(pp[h], off, 64);
    }
    if (lane == 0) {
#pragma unroll
      for (int h = 0; h < 8; ++h) out[(size_t)row * 8 + h] = pp[h];
    }
  }
}

// ---------------- launch ----------------

extern "C" void kernel_launch(void* const* d_in, const int* in_sizes, int n_in,
                              void* d_out, int out_size, void* d_ws, size_t ws_size,
                              hipStream_t stream) {
  const float* X  = (const float*)d_in[0];
  const int*   sg = (const int*)d_in[1];
  const float* W1 = (const float*)d_in[2];
  const float* b1 = (const float*)d_in[3];
  const float* W2 = (const float*)d_in[4];
  const float* b2 = (const float*)d_in[5];
  const float* W3 = (const float*)d_in[6];
  const float* b3 = (const float*)d_in[7];
  const float* Wr = (const float*)d_in[8];
  const float* br = (const float*)d_in[9];
  const float* Wk = (const float*)d_in[10];
  const float* Wq = (const float*)d_in[11];
  float* out = (float*)d_out;

  const size_t szW1T  = 512 * 128 * 2;
  const size_t szWT   = 512 * 512 * 2;
  const size_t szWeff = 640 * 8 * 4;
  const size_t szPart = (size_t)NSEG * RSPL * 256 * 2 * 4;
  const size_t szCar  = (size_t)NSEG * 256 * 2 * 4;
  const size_t szBnd  = (NSEG + 1) * 4;
  const size_t fixed  = szW1T + 3 * szWT + szWeff + szPart + 2 * szCar + szBnd + 256;

  int CH = 0;
  const int cands[6] = {131072, 65536, 32768, 16384, 8192, 4096};
  for (int i = 0; i < 6; ++i) {
    const size_t need = fixed + 2 * (size_t)cands[i] * 512 * 2;  // ping-pong only
    if (need <= ws_size) { CH = cands[i]; break; }
  }
  if (CH == 0) CH = 4096;

  char* p = (char*)d_ws;
  ushortT* W1T  = (ushortT*)p; p += szW1T;
  ushortT* W2T  = (ushortT*)p; p += szWT;
  ushortT* W3T  = (ushortT*)p; p += szWT;
  ushortT* WrT  = (ushortT*)p; p += szWT;
  float*   weff = (float*)p;   p += szWeff;
  float*   part = (float*)p;   p += szPart;
  float*   carA = (float*)p;   p += szCar;
  float*   carB = (float*)p;   p += szCar;
  int*     gbnd = (int*)p;     p += (szBnd + 255) & ~255ull;
  ushortT* p1   = (ushortT*)p; p += (size_t)CH * 512 * 2;
  ushortT* p2   = (ushortT*)p;

  transpose_bf16_kernel<<<(512 * 128 + 255) / 256, 256, 0, stream>>>(W1, W1T, 128, 512);
  transpose_bf16_kernel<<<(512 * 512 + 255) / 256, 256, 0, stream>>>(W2, W2T, 512, 512);
  transpose_bf16_kernel<<<(512 * 512 + 255) / 256, 256, 0, stream>>>(W3, W3T, 512, 512);
  transpose_bf16_kernel<<<(512 * 512 + 255) / 256, 256, 0, stream>>>(Wr, WrT, 512, 512);
  weff_kernel<<<640, 64, 0, stream>>>(Wk, Wq, weff);
  seg_bounds_kernel<<<1, 512, 0, stream>>>(sg, gbnd);
  hipMemsetAsync(carA, 0, szCar, stream);

  int par = 0;
  for (int c0 = 0; c0 < N_TOK; c0 += CH) {
    const int gG = (CH / 128) * 4;
    const int gF = (CH / 4 < 4096) ? CH / 4 : 4096;
    float* cin  = par ? carB : carA;
    float* cout = par ? carA : carB;
    gemm_m97_kernel<128, true,  true,  true ><<<gG, 256, 0, stream>>>(X + (size_t)c0 * 128, W1T, b1, p1);
    gemm_m97_kernel<512, true,  true,  false><<<gG, 256, 0, stream>>>(p1, W2T, b2, p2);
    gemm_m97_kernel<512, true,  true,  false><<<gG, 256, 0, stream>>>(p2, W3T, b3, p1);
    gemm_m97_kernel<512, false, false, false><<<gG, 256, 0, stream>>>(p1, WrT, nullptr, p2);
    seg_sum_kernel <<<NSEG * RSPL, 256, 0, stream>>>(p2, gbnd, part, c0, CH);
    seg_scan2_kernel<<<NSEG * RSPL, 256, 0, stream>>>(p2, p1, gbnd, br, part,
                                                      cin, cout, c0, CH);
    final_kernel<<<gF, 256, 0, stream>>>(X + (size_t)c0 * 128, p1, weff,
                                         out + (size_t)c0 * 8, CH);
    par ^= 1;
  }
}

// Round 10
// 435.370 us; speedup vs baseline: 1.4236x; 1.1549x over previous
//
#include <hip/hip_runtime.h>
#include <hip/hip_bf16.h>
#include <stdint.h>

typedef unsigned short ushortT;
typedef __bf16 bf16x8 __attribute__((ext_vector_type(8)));
typedef float f32x4 __attribute__((ext_vector_type(4)));

#define N_TOK 131072
#define NSEG  256
#define RSPL  8

__device__ __forceinline__ uint32_t f2bf(float f) {
  union { float f; uint32_t u; } c; c.f = f;
  uint32_t u = c.u;
  u += 0x7fffu + ((u >> 16) & 1u);   // RNE
  return u >> 16;
}
__device__ __forceinline__ float bf2f(uint32_t b) {
  union { uint32_t u; float f; } c; c.u = b << 16;
  return c.f;
}

__device__ __forceinline__ void gload_lds16(const void* g, void* l) {
  __builtin_amdgcn_global_load_lds(
      (const __attribute__((address_space(1))) void*)g,
      (__attribute__((address_space(3))) void*)l, 16, 0, 0);
}

// ---------------- prep kernels ----------------

// WT[n*Kd + k] = bf16(W[k*Nd + n]);  W is [Kd][Nd] row-major
__global__ void transpose_bf16_kernel(const float* __restrict__ W, ushortT* __restrict__ WT,
                                      int Kd, int Nd) {
  int i = blockIdx.x * 256 + threadIdx.x;
  if (i < Kd * Nd) {
    int n = i / Kd, k = i % Kd;
    WT[i] = (ushortT)f2bf(W[(size_t)k * Nd + n]);
  }
}

// weffT[h][c] = bf16( sum_d Wk[c,h*128+d]*Wq[h,d] / sqrt(128) ), h<8; rows 8..15 zero
__global__ void weff_kernel(const float* __restrict__ Wk, const float* __restrict__ Wq,
                            ushortT* __restrict__ weffT) {
  const int c = blockIdx.x;       // 640
  const int lane = threadIdx.x;   // 64
  const float rs = 0.08838834764831845f;
#pragma unroll
  for (int h = 0; h < 8; ++h) {
    float acc = Wk[(size_t)c * 1024 + h * 128 + lane] * Wq[h * 128 + lane]
              + Wk[(size_t)c * 1024 + h * 128 + 64 + lane] * Wq[h * 128 + 64 + lane];
#pragma unroll
    for (int off = 32; off >= 1; off >>= 1) acc += __shfl_xor(acc, off, 64);
    if (lane == 0) {
      weffT[h * 640 + c]       = (ushortT)f2bf(acc * rs);
      weffT[(h + 8) * 640 + c] = 0;
    }
  }
}

// gbnd[s] = first index with seg[i] >= s, s in [0, 256]
__global__ void seg_bounds_kernel(const int* __restrict__ seg, int* __restrict__ gbnd) {
  const int s = (int)threadIdx.x + (int)blockIdx.x * 512;
  if (s > NSEG) return;
  int lo = 0, hi = N_TOK;
  while (lo < hi) { int m = (lo + hi) >> 1; if (seg[m] < s) lo = m + 1; else hi = m; }
  gbnd[s] = lo;
}

// ---------------- m97-style GEMM: C[M,512] = relu?(A[M,K] @ W + bias) ----------------
// (unchanged from R9 winner) Tile 128x128, BK=64, 4 waves, single 32KB LDS,
// chunk^(row&7) swizzle both sides, fused X f32->bf16 staging when XF32.

template <int K, bool RELU, bool BIAS, bool XF32>
__global__ __launch_bounds__(256, 2)
void gemm_m97_kernel(const void* __restrict__ Av, const ushortT* __restrict__ BT,
                     const float* __restrict__ bias, ushortT* __restrict__ C) {
  __shared__ ushortT lA[128 * 64];
  __shared__ ushortT lB[128 * 64];
  constexpr int NT = K / 64;

  const int nwg  = (int)gridDim.x;
  const int cpx  = nwg >> 3;
  const int flat = (int)blockIdx.x;
  const int swz  = (flat & 7) * cpx + (flat >> 3);
  const int bm   = swz >> 2;
  const int bn   = swz & 3;

  const int t = (int)threadIdx.x;
  const int w = t >> 6, lane = t & 63;
  const int wm = w >> 1, wn = w & 1;
  const int q = lane >> 4, lr = lane & 15;

  const int srow = t >> 3;
  const int slc  = (t & 7) ^ (srow & 7);

  const ushortT* Ab = nullptr;
  const float*   Xf = nullptr;
  if (XF32) Xf = (const float*)Av + (size_t)(bm * 128 + srow) * 128 + slc * 8;
  else      Ab = (const ushortT*)Av + (size_t)(bm * 128 + srow) * K + slc * 8;
  const ushortT* Bg = BT + (size_t)(bn * 128 + srow) * K + slc * 8;

  f32x4 acc[4][4];
#pragma unroll
  for (int i = 0; i < 4; ++i)
#pragma unroll
    for (int j = 0; j < 4; ++j) acc[i][j] = 0.f;

  const int cc0 = (q ^ (lr & 7)) << 4;
  const int cc1 = ((4 + q) ^ (lr & 7)) << 4;
  const char* lAc = (const char*)lA;
  const char* lBc = (const char*)lB;

#pragma unroll 1
  for (int kt = 0; kt < NT; ++kt) {
    if (XF32) {
      const float* src = Xf + kt * 64;
#pragma unroll
      for (int j = 0; j < 4; ++j) {
        const float4 v0 = *(const float4*)(src + (size_t)j * 32 * 128);
        const float4 v1 = *(const float4*)(src + (size_t)j * 32 * 128 + 4);
        uint4 pk;
        pk.x = f2bf(v0.x) | (f2bf(v0.y) << 16);
        pk.y = f2bf(v0.z) | (f2bf(v0.w) << 16);
        pk.z = f2bf(v1.x) | (f2bf(v1.y) << 16);
        pk.w = f2bf(v1.z) | (f2bf(v1.w) << 16);
        *(uint4*)((char*)lA + j * 4096 + t * 16) = pk;
      }
    } else {
      const ushortT* src = Ab + kt * 64;
#pragma unroll
      for (int j = 0; j < 4; ++j)
        gload_lds16(src + (size_t)j * 32 * K, (char*)lA + j * 4096 + t * 16);
    }
    {
      const ushortT* src = Bg + kt * 64;
#pragma unroll
      for (int j = 0; j < 4; ++j)
        gload_lds16(src + (size_t)j * 32 * K, (char*)lB + j * 4096 + t * 16);
    }
    __syncthreads();

    bf16x8 a0[4], a1[4], b0[4], b1[4];
#pragma unroll
    for (int m = 0; m < 4; ++m) {
      const int ro = (wm * 64 + m * 16 + lr) * 128;
      a0[m] = *(const bf16x8*)(lAc + ro + cc0);
      a1[m] = *(const bf16x8*)(lAc + ro + cc1);
    }
#pragma unroll
    for (int n = 0; n < 4; ++n) {
      const int ro = (wn * 64 + n * 16 + lr) * 128;
      b0[n] = *(const bf16x8*)(lBc + ro + cc0);
      b1[n] = *(const bf16x8*)(lBc + ro + cc1);
    }

    __builtin_amdgcn_s_setprio(1);
#pragma unroll
    for (int n = 0; n < 4; ++n)
#pragma unroll
      for (int m = 0; m < 4; ++m)
        acc[m][n] = __builtin_amdgcn_mfma_f32_16x16x32_bf16(a0[m], b0[n], acc[m][n], 0, 0, 0);
#pragma unroll
    for (int n = 0; n < 4; ++n)
#pragma unroll
      for (int m = 0; m < 4; ++m)
        acc[m][n] = __builtin_amdgcn_mfma_f32_16x16x32_bf16(a1[m], b1[n], acc[m][n], 0, 0, 0);
    __builtin_amdgcn_s_setprio(0);

    __syncthreads();
  }

  const int row0 = bm * 128 + wm * 64 + q * 4;
  const int col0 = bn * 128 + wn * 64 + lr;
#pragma unroll
  for (int n = 0; n < 4; ++n) {
    const int col = col0 + n * 16;
    const float bvv = BIAS ? bias[col] : 0.f;
#pragma unroll
    for (int m = 0; m < 4; ++m) {
#pragma unroll
      for (int r = 0; r < 4; ++r) {
        float v = acc[m][n][r] + bvv;
        if (RELU) v = fmaxf(v, 0.f);
        C[(size_t)(row0 + m * 16 + r) * 512 + col] = (ushortT)f2bf(v);
      }
    }
  }
}

// ---------------- two-pass segment prefix-mean (unchanged) ----------------

__global__ __launch_bounds__(256)
void seg_sum_kernel(const ushortT* __restrict__ z, const int* __restrict__ gbnd,
                    float* __restrict__ part, int c0, int rows) {
  const int s  = (int)blockIdx.x >> 3;
  const int rg = (int)blockIdx.x & 7;
  const int t  = (int)threadIdx.x;

  const int gb0 = gbnd[s], gb1 = gbnd[s + 1];
  int beg = gb0 > c0 ? gb0 : c0;
  int end = gb1 < c0 + rows ? gb1 : c0 + rows;
  int len = end - beg; if (len < 0) len = 0;
  const int r0 = beg + ((len * rg) >> 3);
  const int r1 = beg + ((len * (rg + 1)) >> 3);

  float a0 = 0.f, a1 = 0.f;
  const uint32_t* __restrict__ zp = (const uint32_t*)z;
  int r = r0;
  for (; r + 8 <= r1; r += 8) {
    uint32_t v[8];
#pragma unroll
    for (int i = 0; i < 8; ++i) v[i] = zp[(size_t)(r + i - c0) * 256 + t];
#pragma unroll
    for (int i = 0; i < 8; ++i) { a0 += bf2f(v[i] & 0xffffu); a1 += bf2f(v[i] >> 16); }
  }
  for (; r < r1; ++r) {
    const uint32_t v = zp[(size_t)(r - c0) * 256 + t];
    a0 += bf2f(v & 0xffffu); a1 += bf2f(v >> 16);
  }
  float2 pv; pv.x = a0; pv.y = a1;
  ((float2*)part)[(s * 8 + rg) * 256 + t] = pv;
}

__global__ __launch_bounds__(256)
void seg_scan2_kernel(const ushortT* __restrict__ z, ushortT* __restrict__ gout,
                      const int* __restrict__ gbnd, const float* __restrict__ br,
                      const float* __restrict__ part,
                      const float* __restrict__ cin, float* __restrict__ cout,
                      int c0, int rows) {
  const int s  = (int)blockIdx.x >> 3;
  const int rg = (int)blockIdx.x & 7;
  const int t  = (int)threadIdx.x;

  const int gb0 = gbnd[s], gb1 = gbnd[s + 1];
  int beg = gb0 > c0 ? gb0 : c0;
  int end = gb1 < c0 + rows ? gb1 : c0 + rows;
  int len = end - beg; if (len < 0) len = 0;
  const int r0 = beg + ((len * rg) >> 3);
  const int r1 = beg + ((len * (rg + 1)) >> 3);

  const float2 cv = ((const float2*)cin)[s * 256 + t];
  float a0 = cv.x, a1 = cv.y;
  for (int q2 = 0; q2 < rg; ++q2) {
    const float2 pv = ((const float2*)part)[(s * 8 + q2) * 256 + t];
    a0 += pv.x; a1 += pv.y;
  }
  int cb = c0 - gb0; if (cb < 0) cb = 0;
  const int seglen = gb1 - gb0; if (cb > seglen) cb = seglen;
  const int cnt0 = cb + (r0 - beg);

  const float b0 = br[2 * t], b1v = br[2 * t + 1];
  const uint32_t* __restrict__ zp = (const uint32_t*)z;
  uint32_t* __restrict__ gp = (uint32_t*)gout;

  int r = r0;
  for (; r + 8 <= r1; r += 8) {
    uint32_t v[8];
#pragma unroll
    for (int i = 0; i < 8; ++i) v[i] = zp[(size_t)(r + i - c0) * 256 + t];
#pragma unroll
    for (int i = 0; i < 8; ++i) {
      a0 += bf2f(v[i] & 0xffffu);
      a1 += bf2f(v[i] >> 16);
      const float inv = 1.0f / (float)(cnt0 + (r + i) - r0 + 1);
      const float g0 = fmaxf(fmaf(a0, inv, b0), 0.f);
      const float g1 = fmaxf(fmaf(a1, inv, b1v), 0.f);
      gp[(size_t)(r + i - c0) * 256 + t] = f2bf(g0) | (f2bf(g1) << 16);
    }
  }
  for (; r < r1; ++r) {
    const uint32_t v = zp[(size_t)(r - c0) * 256 + t];
    a0 += bf2f(v & 0xffffu);
    a1 += bf2f(v >> 16);
    const float inv = 1.0f / (float)(cnt0 + r - r0 + 1);
    const float g0 = fmaxf(fmaf(a0, inv, b0), 0.f);
    const float g1 = fmaxf(fmaf(a1, inv, b1v), 0.f);
    gp[(size_t)(r - c0) * 256 + t] = f2bf(g0) | (f2bf(g1) << 16);
  }

  if (rg == 7) {
    float2 co; co.x = a0; co.y = a1;
    ((float2*)cout)[s * 256 + t] = co;
  }
}

// ---------------- final via MFMA: out[n,h] = [X | g][n,:] @ weffT^T ----------------
// Block = 128 rows, 4 waves; wave = 2 row-tiles of 16 (acc 2x f32x4).
// A-frag: row=lr, k=q*8..+8: k<128 from X (f32->bf16 cvt), k>=128 from g (bf16 direct).
// B-frag: weffT rows (h=lr), staged in LDS with 1296B row pitch (pad kills the
// 16-way bank conflict: stride%32banks = 4 -> 8 quads x 2-way = free).
// D: col(lane&15)=head (only <8 stored), row = q*4+r. No cross-lane reduce.

__global__ __launch_bounds__(256)
void final_mfma_kernel(const float* __restrict__ X, const ushortT* __restrict__ g,
                       const ushortT* __restrict__ weffT, float* __restrict__ out) {
  __shared__ char lw[16 * 1296];
  const int t = (int)threadIdx.x;

  // stage weffT [16][640] bf16 -> LDS rows with 1296B pitch (1280 chunks of 16B)
#pragma unroll
  for (int i = 0; i < 5; ++i) {
    const int idx = i * 256 + t;          // 0..1279
    const int row = idx / 80, c = idx % 80;
    *(uint4*)(lw + row * 1296 + c * 16) =
        *(const uint4*)((const char*)weffT + row * 1280 + c * 16);
  }
  __syncthreads();

  const int wv = t >> 6, lane = t & 63;
  const int q = lane >> 4, lr = lane & 15;
  const int rbase = (int)blockIdx.x * 128 + wv * 32;

  f32x4 acc[2];
  acc[0] = 0.f; acc[1] = 0.f;

#pragma unroll
  for (int kk = 0; kk < 20; ++kk) {
    const bf16x8 b = *(const bf16x8*)(lw + lr * 1296 + kk * 64 + q * 16);
#pragma unroll
    for (int mt = 0; mt < 2; ++mt) {
      const int row = rbase + mt * 16 + lr;
      union { ushortT u[8]; bf16x8 v; } a;
      if (kk < 4) {
        const float* xr = X + (size_t)row * 128 + kk * 32 + q * 8;
        const float4 v0 = *(const float4*)xr;
        const float4 v1 = *(const float4*)(xr + 4);
        a.u[0] = (ushortT)f2bf(v0.x); a.u[1] = (ushortT)f2bf(v0.y);
        a.u[2] = (ushortT)f2bf(v0.z); a.u[3] = (ushortT)f2bf(v0.w);
        a.u[4] = (ushortT)f2bf(v1.x); a.u[5] = (ushortT)f2bf(v1.y);
        a.u[6] = (ushortT)f2bf(v1.z); a.u[7] = (ushortT)f2bf(v1.w);
      } else {
        a.v = *(const bf16x8*)(g + (size_t)row * 512 + (kk - 4) * 32 + q * 8);
      }
      acc[mt] = __builtin_amdgcn_mfma_f32_16x16x32_bf16(a.v, b, acc[mt], 0, 0, 0);
    }
  }

  if (lr < 8) {
#pragma unroll
    for (int mt = 0; mt < 2; ++mt)
#pragma unroll
      for (int r = 0; r < 4; ++r)
        out[(size_t)(rbase + mt * 16 + q * 4 + r) * 8 + lr] = acc[mt][r];
  }
}

// ---------------- launch ----------------

extern "C" void kernel_launch(void* const* d_in, const int* in_sizes, int n_in,
                              void* d_out, int out_size, void* d_ws, size_t ws_size,
                              hipStream_t stream) {
  const float* X  = (const float*)d_in[0];
  const int*   sg = (const int*)d_in[1];
  const float* W1 = (const float*)d_in[2];
  const float* b1 = (const float*)d_in[3];
  const float* W2 = (const float*)d_in[4];
  const float* b2 = (const float*)d_in[5];
  const float* W3 = (const float*)d_in[6];
  const float* b3 = (const float*)d_in[7];
  const float* Wr = (const float*)d_in[8];
  const float* br = (const float*)d_in[9];
  const float* Wk = (const float*)d_in[10];
  const float* Wq = (const float*)d_in[11];
  float* out = (float*)d_out;

  const size_t szW1T  = 512 * 128 * 2;
  const size_t szWT   = 512 * 512 * 2;
  const size_t szWeff = 16 * 640 * 2;
  const size_t szPart = (size_t)NSEG * RSPL * 256 * 2 * 4;
  const size_t szCar  = (size_t)NSEG * 256 * 2 * 4;
  const size_t szBnd  = (NSEG + 1) * 4;
  const size_t fixed  = szW1T + 3 * szWT + szWeff + szPart + 2 * szCar + szBnd + 512;

  int CH = 0;
  const int cands[6] = {131072, 65536, 32768, 16384, 8192, 4096};
  for (int i = 0; i < 6; ++i) {
    const size_t need = fixed + 2 * (size_t)cands[i] * 512 * 2;  // ping-pong only
    if (need <= ws_size) { CH = cands[i]; break; }
  }
  if (CH == 0) CH = 4096;

  char* p = (char*)d_ws;
  ushortT* W1T   = (ushortT*)p; p += szW1T;
  ushortT* W2T   = (ushortT*)p; p += szWT;
  ushortT* W3T   = (ushortT*)p; p += szWT;
  ushortT* WrT   = (ushortT*)p; p += szWT;
  ushortT* weffT = (ushortT*)p; p += szWeff;
  float*   part  = (float*)p;   p += szPart;
  float*   carA  = (float*)p;   p += szCar;
  float*   carB  = (float*)p;   p += szCar;
  int*     gbnd  = (int*)p;     p += (szBnd + 255) & ~255ull;
  ushortT* p1    = (ushortT*)p; p += (size_t)CH * 512 * 2;
  ushortT* p2    = (ushortT*)p;

  transpose_bf16_kernel<<<(512 * 128 + 255) / 256, 256, 0, stream>>>(W1, W1T, 128, 512);
  transpose_bf16_kernel<<<(512 * 512 + 255) / 256, 256, 0, stream>>>(W2, W2T, 512, 512);
  transpose_bf16_kernel<<<(512 * 512 + 255) / 256, 256, 0, stream>>>(W3, W3T, 512, 512);
  transpose_bf16_kernel<<<(512 * 512 + 255) / 256, 256, 0, stream>>>(Wr, WrT, 512, 512);
  weff_kernel<<<640, 64, 0, stream>>>(Wk, Wq, weffT);
  seg_bounds_kernel<<<1, 512, 0, stream>>>(sg, gbnd);
  hipMemsetAsync(carA, 0, szCar, stream);

  int par = 0;
  for (int c0 = 0; c0 < N_TOK; c0 += CH) {
    const int gG = (CH / 128) * 4;
    float* cin  = par ? carB : carA;
    float* cout = par ? carA : carB;
    gemm_m97_kernel<128, true,  true,  true ><<<gG, 256, 0, stream>>>(X + (size_t)c0 * 128, W1T, b1, p1);
    gemm_m97_kernel<512, true,  true,  false><<<gG, 256, 0, stream>>>(p1, W2T, b2, p2);
    gemm_m97_kernel<512, true,  true,  false><<<gG, 256, 0, stream>>>(p2, W3T, b3, p1);
    gemm_m97_kernel<512, false, false, false><<<gG, 256, 0, stream>>>(p1, WrT, nullptr, p2);
    seg_sum_kernel <<<NSEG * RSPL, 256, 0, stream>>>(p2, gbnd, part, c0, CH);
    seg_scan2_kernel<<<NSEG * RSPL, 256, 0, stream>>>(p2, p1, gbnd, br, part,
                                                      cin, cout, c0, CH);
    final_mfma_kernel<<<CH / 128, 256, 0, stream>>>(X + (size_t)c0 * 128, p1, weffT,
                                                    out + (size_t)c0 * 8);
    par ^= 1;
  }
}